// Round 6
// baseline (473.484 us; speedup 1.0000x reference)
//
#include <hip/hip_runtime.h>

typedef __bf16 bf16x8 __attribute__((ext_vector_type(8)));
typedef float  f32x4  __attribute__((ext_vector_type(4)));
typedef unsigned int u32x4 __attribute__((ext_vector_type(4)));

#define B_   2
#define N_   512
#define ND_  256
#define ED_  64
#define NH_  8
#define DH_  32

// LDS row stride in shorts. 84: conflict-free a-frag reads (banks 10*l15+4*q4
// mod 32 all distinct; SQ_LDS_BANK_CONFLICT measured 0 in round 5 vs 2.1M at 72).
#define LROW 84

static __device__ __forceinline__ unsigned pack_bf16(float a, float b) {
    unsigned short ua = __builtin_bit_cast(unsigned short, (__bf16)a);
    unsigned short ub = __builtin_bit_cast(unsigned short, (__bf16)b);
    return (unsigned)ua | ((unsigned)ub << 16);
}

// ---------------- prep kernel 1: edge-weight fp32 -> bf16 (row-major [256][64])
__global__ __launch_bounds__(256) void cvt_w_kernel(
    const float* __restrict__ wq, const float* __restrict__ wk,
    const float* __restrict__ wv, unsigned short* __restrict__ w16)
{
    int id = blockIdx.x * 256 + threadIdx.x;          // 0..49151
    const float* src = (id < 16384) ? wq : (id < 32768 ? wk : wv);
    int idx = id & 16383;
    w16[id] = __builtin_bit_cast(unsigned short, (__bf16)src[idx]);
}

// ---------------- prep kernel 1b: transpose node weights -> Wt[m][k][c] fp32
__global__ __launch_bounds__(256) void trans_w_kernel(
    const float* __restrict__ Wq, const float* __restrict__ Wk,
    const float* __restrict__ Wv, float* __restrict__ Wt)
{
    __shared__ float t[32][33];
    const int bx = blockIdx.x;        // 0..191 = 3 mats * 64 tiles
    const int m  = bx >> 6;
    const int t6 = bx & 63;
    const int cb = (t6 >> 3) << 5;    // c-block
    const int kb = (t6 & 7) << 5;     // k-block
    const float* W = (m == 0) ? Wq : (m == 1 ? Wk : Wv);
    const int tx = threadIdx.x & 31, ty = threadIdx.x >> 5;   // 32 x 8
    #pragma unroll
    for (int s = 0; s < 4; s++)
        t[ty + 8 * s][tx] = W[(size_t)(cb + ty + 8 * s) * ND_ + kb + tx];
    __syncthreads();
    float* dst = Wt + (size_t)m * ND_ * ND_;
    #pragma unroll
    for (int s = 0; s < 4; s++)
        dst[(size_t)(kb + ty + 8 * s) * ND_ + cb + tx] = t[tx][ty + 8 * s];
}

// ------- prep kernel 2: node projections with coalesced (transposed) weights.
// Q -> row-major head-split Qh[bh][i][32].
// K,V -> KVp in MFMA C-fragment order so attn loads are lane-linear:
//   KVp float idx = ((bh*32 + j/16)*4 + set)*256 + (((d>>2)&3)*16 + (j&15))*4 + (d&3)
//   set: 0,1 = K halves (d<16 / d>=16), 2,3 = V halves.
__global__ __launch_bounds__(256) void qkv_kernel(
    const float* __restrict__ node, const float* __restrict__ Wt,
    const float* __restrict__ bnq, const float* __restrict__ bnk,
    const float* __restrict__ bnv, const float* __restrict__ beq,
    const float* __restrict__ bek, const float* __restrict__ bev,
    float* __restrict__ Qh, float* __restrict__ KVp)
{
    __shared__ float xs[4][ND_];
    const int c   = threadIdx.x;
    const int m   = blockIdx.x >> 8;       // 0=Q 1=K 2=V
    const int grp = blockIdx.x & 255;
    const int g0  = grp * 4;
    {
        const int r = c >> 6, col4 = (c & 63) * 4;
        const float4 v = *reinterpret_cast<const float4*>(node + (size_t)(g0 + r) * ND_ + col4);
        *reinterpret_cast<float4*>(&xs[r][col4]) = v;
    }
    __syncthreads();

    const float* Wm = Wt + (size_t)m * ND_ * ND_;
    float acc[4] = {0.f, 0.f, 0.f, 0.f};
    for (int k = 0; k < ND_; k += 4) {
        const float w0 = Wm[(size_t)(k + 0) * ND_ + c];
        const float w1 = Wm[(size_t)(k + 1) * ND_ + c];
        const float w2 = Wm[(size_t)(k + 2) * ND_ + c];
        const float w3 = Wm[(size_t)(k + 3) * ND_ + c];
        #pragma unroll
        for (int rr = 0; rr < 4; rr++) {
            const float4 x = *reinterpret_cast<const float4*>(&xs[rr][k]);
            acc[rr] += x.x * w0 + x.y * w1 + x.z * w2 + x.w * w3;
        }
    }
    const float bias = (m == 0) ? (bnq[c] + beq[c])
                     : (m == 1) ? (bnk[c] + bek[c])
                                : (bnv[c] + bev[c]);
    const int h = c >> 5, d = c & 31;
    #pragma unroll
    for (int rr = 0; rr < 4; rr++) {
        const int g  = g0 + rr;
        const int bb = g >> 9, ii = g & (N_ - 1);
        const int bh = bb * NH_ + h;
        const float y = acc[rr] + bias;
        if (m == 0) {
            Qh[((size_t)bh * N_ + ii) * DH_ + d] = y;
        } else {
            const int set = ((m == 1) ? 0 : 2) + (d >> 4);
            const size_t idx = (((size_t)bh * 32 + (ii >> 4)) * 4 + set) * 256
                             + (size_t)((((d >> 2) & 3) * 16 + (ii & 15)) * 4 + (d & 3));
            KVp[idx] = y;
        }
    }
}

// ---------------- main fused kernel: one block per (b, 4 i-rows), 8 waves = 8 heads.
// Same pipeline as rounds 2-5, but FULLY HAND-SCALARIZED: no ext_vector arrays
// anywhere (rule #20: runtime-indexed ext_vector arrays go to localMem, which
// is what produced rounds 2-5's 442 MB of scratch traffic at VGPR_Count==128 --
// the 128 was the register demand of the NON-array state, not an occupancy cap).
// All per-row state (Cq, o, l) and W fragments are named scalars with only
// compile-time component indices.
__global__ __attribute__((amdgpu_flat_work_group_size(512, 512),
                          amdgpu_waves_per_eu(2, 2)))
void attn_kernel(
    const float* __restrict__ edge,
    const float* __restrict__ Qh, const float* __restrict__ KVp,
    const unsigned short* __restrict__ W16, float* __restrict__ out)
{
    __shared__ unsigned short lds_[2][4][64 * LROW];   // [buf][i-row][64 rows]

    const int tid  = threadIdx.x;
    const int lane = tid & 63;
    const int h    = tid >> 6;       // wave id == head
    const int q4   = lane >> 4;
    const int l15  = lane & 15;
    const int blk  = blockIdx.x;     // 0..255
    const int b    = blk >> 7;
    const int i0   = (blk & 127) * 4;
    const int bh   = b * NH_ + h;

#define LD8(P) __builtin_bit_cast(bf16x8, *reinterpret_cast<const u32x4*>(P))

    // W A-operand frags, 12 named vars: w<m><hf><ks>; A[m=l15][k=q4*8+kk]
    const unsigned short* wb = W16 + (h * DH_ + l15) * ED_ + q4 * 8;
#define WLOAD(MO, HF, KS) LD8(wb + (MO) * (ND_ * ED_) + (HF) * (16 * ED_) + (KS) * 32)
    const bf16x8 wq00 = WLOAD(0, 0, 0), wq01 = WLOAD(0, 0, 1);
    const bf16x8 wq10 = WLOAD(0, 1, 0), wq11 = WLOAD(0, 1, 1);
    const bf16x8 wk00 = WLOAD(1, 0, 0), wk01 = WLOAD(1, 0, 1);
    const bf16x8 wk10 = WLOAD(1, 1, 0), wk11 = WLOAD(1, 1, 1);
    const bf16x8 wv00 = WLOAD(2, 0, 0), wv01 = WLOAD(2, 0, 1);
    const bf16x8 wv10 = WLOAD(2, 1, 0), wv11 = WLOAD(2, 1, 1);
#undef WLOAD

    // Q C-init (row d = q4*4+r, broadcast over j=l15), 8 named vars
    const float* Qrow = Qh + ((size_t)bh * N_ + i0) * DH_ + q4 * 4;
    const f32x4 cq00 = *reinterpret_cast<const f32x4*>(Qrow + 0 * DH_);
    const f32x4 cq01 = *reinterpret_cast<const f32x4*>(Qrow + 0 * DH_ + 16);
    const f32x4 cq10 = *reinterpret_cast<const f32x4*>(Qrow + 1 * DH_);
    const f32x4 cq11 = *reinterpret_cast<const f32x4*>(Qrow + 1 * DH_ + 16);
    const f32x4 cq20 = *reinterpret_cast<const f32x4*>(Qrow + 2 * DH_);
    const f32x4 cq21 = *reinterpret_cast<const f32x4*>(Qrow + 2 * DH_ + 16);
    const f32x4 cq30 = *reinterpret_cast<const f32x4*>(Qrow + 3 * DH_);
    const f32x4 cq31 = *reinterpret_cast<const f32x4*>(Qrow + 3 * DH_ + 16);

    // lane-linear K/V fragment base: per jg, sets at +0,+64,+128,+192 (f32x4)
    const f32x4* kvb = reinterpret_cast<const f32x4*>(KVp + (size_t)bh * 32 * 1024) + lane;

    const float* eb0 = edge + (size_t)(b * N_ + i0) * N_ * ED_;   // row stride N_*ED_

    float l0 = 0.f, l1 = 0.f, l2 = 0.f, l3 = 0.f;
    f32x4 oa0 = {0.f,0.f,0.f,0.f}, ob0 = {0.f,0.f,0.f,0.f};
    f32x4 oa1 = {0.f,0.f,0.f,0.f}, ob1 = {0.f,0.f,0.f,0.f};
    f32x4 oa2 = {0.f,0.f,0.f,0.f}, ob2 = {0.f,0.f,0.f,0.f};
    f32x4 oa3 = {0.f,0.f,0.f,0.f}, ob3 = {0.f,0.f,0.f,0.f};
    const float scale = 0.17677669529663687f;   // 1/sqrt(32)

#define KV_PREFETCH(KA0, KA1, VA0, VA1, JG) do {                               \
        const f32x4* pp_ = kvb + (size_t)((JG) & 31) * 256;                    \
        KA0 = pp_[0]; KA1 = pp_[64]; VA0 = pp_[128]; VA1 = pp_[192];           \
    } while (0)

#define ISSUE_HALF(gA, gB, gC, gD, H, CN) do {                                 \
        const float4* p0_ = reinterpret_cast<const float4*>(eb0 + (size_t)((H)*2)     * (N_*ED_) + (CN) * 4096); \
        const float4* p1_ = reinterpret_cast<const float4*>(eb0 + (size_t)((H)*2 + 1) * (N_*ED_) + (CN) * 4096); \
        gA = p0_[tid]; gB = p0_[tid + 512]; gC = p1_[tid]; gD = p1_[tid + 512]; \
    } while (0)

#define WRITE_HALF(gA, gB, gC, gD, H, NB) do {                                 \
        unsigned short* b0_ = &lds_[NB][(H)*2][0];                             \
        unsigned short* b1_ = &lds_[NB][(H)*2 + 1][0];                         \
        { uint2 v_ = {pack_bf16(gA.x, gA.y), pack_bf16(gA.z, gA.w)};           \
          *reinterpret_cast<uint2*>(b0_ + (tid >> 4) * LROW + (tid & 15) * 4) = v_; } \
        { const int f_ = tid + 512;                                            \
          uint2 v_ = {pack_bf16(gB.x, gB.y), pack_bf16(gB.z, gB.w)};           \
          *reinterpret_cast<uint2*>(b0_ + (f_ >> 4) * LROW + (f_ & 15) * 4) = v_; } \
        { uint2 v_ = {pack_bf16(gC.x, gC.y), pack_bf16(gC.z, gC.w)};           \
          *reinterpret_cast<uint2*>(b1_ + (tid >> 4) * LROW + (tid & 15) * 4) = v_; } \
        { const int f_ = tid + 512;                                            \
          uint2 v_ = {pack_bf16(gD.x, gD.y), pack_bf16(gD.z, gD.w)};           \
          *reinterpret_cast<uint2*>(b1_ + (f_ >> 4) * LROW + (f_ & 15) * 4) = v_; } \
    } while (0)

// One i-row's sub-step: MFMA cluster -> score -> exp -> accumulate. All named.
#define SUB_II(AA, AB, CQ0, CQ1, KA0, KA1, VA0, VA1, O0, O1, LACC) do {        \
        __builtin_amdgcn_s_setprio(1);                                         \
        f32x4 eq0_ = __builtin_amdgcn_mfma_f32_16x16x32_bf16(wq00, AA, CQ0, 0, 0, 0); \
        f32x4 eq1_ = __builtin_amdgcn_mfma_f32_16x16x32_bf16(wq10, AA, CQ1, 0, 0, 0); \
        f32x4 ek0_ = __builtin_amdgcn_mfma_f32_16x16x32_bf16(wk00, AA, KA0, 0, 0, 0); \
        f32x4 ek1_ = __builtin_amdgcn_mfma_f32_16x16x32_bf16(wk10, AA, KA1, 0, 0, 0); \
        f32x4 ev0_ = __builtin_amdgcn_mfma_f32_16x16x32_bf16(wv00, AA, VA0, 0, 0, 0); \
        f32x4 ev1_ = __builtin_amdgcn_mfma_f32_16x16x32_bf16(wv10, AA, VA1, 0, 0, 0); \
        eq0_ = __builtin_amdgcn_mfma_f32_16x16x32_bf16(wq01, AB, eq0_, 0, 0, 0);      \
        eq1_ = __builtin_amdgcn_mfma_f32_16x16x32_bf16(wq11, AB, eq1_, 0, 0, 0);      \
        ek0_ = __builtin_amdgcn_mfma_f32_16x16x32_bf16(wk01, AB, ek0_, 0, 0, 0);      \
        ek1_ = __builtin_amdgcn_mfma_f32_16x16x32_bf16(wk11, AB, ek1_, 0, 0, 0);      \
        ev0_ = __builtin_amdgcn_mfma_f32_16x16x32_bf16(wv01, AB, ev0_, 0, 0, 0);      \
        ev1_ = __builtin_amdgcn_mfma_f32_16x16x32_bf16(wv11, AB, ev1_, 0, 0, 0);      \
        __builtin_amdgcn_s_setprio(0);                                         \
        float ta_ = eq0_[0]*ek0_[0] + eq0_[1]*ek0_[1];                         \
        float tb_ = eq0_[2]*ek0_[2] + eq0_[3]*ek0_[3];                         \
        float tc_ = eq1_[0]*ek1_[0] + eq1_[1]*ek1_[1];                         \
        float td_ = eq1_[2]*ek1_[2] + eq1_[3]*ek1_[3];                         \
        float t_ = (ta_ + tb_) + (tc_ + td_);                                  \
        t_ += __shfl_xor(t_, 16, 64);                                          \
        t_ += __shfl_xor(t_, 32, 64);                                          \
        const float p_ = __expf(fmaf(t_, scale, -4.f));                        \
        LACC += p_;                                                            \
        O0 += ev0_ * p_;                                                       \
        O1 += ev1_ * p_;                                                       \
    } while (0)

// One sub-step for all 4 i-rows (constant LDS offsets), then refill the KV set.
#define DO_SUB(SI, KA0, KA1, VA0, VA1) do {                                    \
        const unsigned short* cb_ = &lds_[ch & 1][0][0]                        \
                                  + ((SI) * 16 + l15) * LROW + q4 * 8;         \
        const bf16x8 aA0_ = LD8(cb_ + 0 * (64 * LROW));                        \
        const bf16x8 aB0_ = LD8(cb_ + 0 * (64 * LROW) + 32);                   \
        const bf16x8 aA1_ = LD8(cb_ + 1 * (64 * LROW));                        \
        const bf16x8 aB1_ = LD8(cb_ + 1 * (64 * LROW) + 32);                   \
        const bf16x8 aA2_ = LD8(cb_ + 2 * (64 * LROW));                        \
        const bf16x8 aB2_ = LD8(cb_ + 2 * (64 * LROW) + 32);                   \
        const bf16x8 aA3_ = LD8(cb_ + 3 * (64 * LROW));                        \
        const bf16x8 aB3_ = LD8(cb_ + 3 * (64 * LROW) + 32);                   \
        SUB_II(aA0_, aB0_, cq00, cq01, KA0, KA1, VA0, VA1, oa0, ob0, l0);      \
        SUB_II(aA1_, aB1_, cq10, cq11, KA0, KA1, VA0, VA1, oa1, ob1, l1);      \
        SUB_II(aA2_, aB2_, cq20, cq21, KA0, KA1, VA0, VA1, oa2, ob2, l2);      \
        SUB_II(aA3_, aB3_, cq30, cq31, KA0, KA1, VA0, VA1, oa3, ob3, l3);      \
        KV_PREFETCH(KA0, KA1, VA0, VA1, ch * 4 + (SI) + 2);                    \
    } while (0)

    // ---- prologue: KV jg=0,1 first (oldest in queue), then stage chunk 0
    f32x4 k0a, k0b, v0a, v0b, k1a, k1b, v1a, v1b;
    KV_PREFETCH(k0a, k0b, v0a, v0b, 0);
    KV_PREFETCH(k1a, k1b, v1a, v1b, 1);
    float4 ga0, ga1, ga2, ga3, gb0, gb1, gb2, gb3;
    ISSUE_HALF(ga0, ga1, ga2, ga3, 0, 0);
    ISSUE_HALF(gb0, gb1, gb2, gb3, 1, 0);
    WRITE_HALF(ga0, ga1, ga2, ga3, 0, 0);
    WRITE_HALF(gb0, gb1, gb2, gb3, 1, 0);
    __syncthreads();

    #pragma unroll 1
    for (int ch = 0; ch < 8; ch++) {
        if (ch < 7) ISSUE_HALF(ga0, ga1, ga2, ga3, 0, ch + 1);
        DO_SUB(0, k0a, k0b, v0a, v0b);
        DO_SUB(1, k1a, k1b, v1a, v1b);
        if (ch < 7) {
            WRITE_HALF(ga0, ga1, ga2, ga3, 0, (ch + 1) & 1);
            ISSUE_HALF(gb0, gb1, gb2, gb3, 1, ch + 1);
        }
        DO_SUB(2, k0a, k0b, v0a, v0b);
        DO_SUB(3, k1a, k1b, v1a, v1b);
        if (ch < 7) WRITE_HALF(gb0, gb1, gb2, gb3, 1, (ch + 1) & 1);
        __syncthreads();
    }

    // final reductions over the 16 j-classes (l15); hand-unrolled, static idx
#define RSTEP(LACC, O0, O1, MASK) do {                                         \
        LACC += __shfl_xor(LACC, MASK, 64);                                    \
        O0[0] += __shfl_xor(O0[0], MASK, 64);                                  \
        O0[1] += __shfl_xor(O0[1], MASK, 64);                                  \
        O0[2] += __shfl_xor(O0[2], MASK, 64);                                  \
        O0[3] += __shfl_xor(O0[3], MASK, 64);                                  \
        O1[0] += __shfl_xor(O1[0], MASK, 64);                                  \
        O1[1] += __shfl_xor(O1[1], MASK, 64);                                  \
        O1[2] += __shfl_xor(O1[2], MASK, 64);                                  \
        O1[3] += __shfl_xor(O1[3], MASK, 64);                                  \
    } while (0)
#define RED4(LACC, O0, O1)                                                     \
        RSTEP(LACC, O0, O1, 1); RSTEP(LACC, O0, O1, 2);                        \
        RSTEP(LACC, O0, O1, 4); RSTEP(LACC, O0, O1, 8)

    RED4(l0, oa0, ob0);
    RED4(l1, oa1, ob1);
    RED4(l2, oa2, ob2);
    RED4(l3, oa3, ob3);

#define OUT_II(II, LACC, O0, O1) do {                                          \
        const float inv_ = 1.f / LACC;                                         \
        float* orow_ = out + ((size_t)(b * N_ + i0 + (II))) * ND_ + h * DH_ + q4 * 4; \
        float4 va_ = {O0[0] * inv_, O0[1] * inv_, O0[2] * inv_, O0[3] * inv_}; \
        float4 vb_ = {O1[0] * inv_, O1[1] * inv_, O1[2] * inv_, O1[3] * inv_}; \
        *reinterpret_cast<float4*>(orow_)      = va_;                          \
        *reinterpret_cast<float4*>(orow_ + 16) = vb_;                          \
    } while (0)

    if (l15 == 0) {
        OUT_II(0, l0, oa0, ob0);
        OUT_II(1, l1, oa1, ob1);
        OUT_II(2, l2, oa2, ob2);
        OUT_II(3, l3, oa3, ob3);
    }
#undef KV_PREFETCH
#undef ISSUE_HALF
#undef WRITE_HALF
#undef SUB_II
#undef DO_SUB
#undef RSTEP
#undef RED4
#undef OUT_II
#undef LD8
}

extern "C" void kernel_launch(void* const* d_in, const int* in_sizes, int n_in,
                              void* d_out, int out_size, void* d_ws, size_t ws_size,
                              hipStream_t stream) {
    const float* node = (const float*)d_in[0];
    const float* edge = (const float*)d_in[1];
    const float* Wnq  = (const float*)d_in[2];
    const float* bnq  = (const float*)d_in[3];
    const float* Wnk  = (const float*)d_in[4];
    const float* bnk  = (const float*)d_in[5];
    const float* Wnv  = (const float*)d_in[6];
    const float* bnv  = (const float*)d_in[7];
    const float* Weq  = (const float*)d_in[8];
    const float* beq  = (const float*)d_in[9];
    const float* Wek  = (const float*)d_in[10];
    const float* bek  = (const float*)d_in[11];
    const float* Wev  = (const float*)d_in[12];
    const float* bev  = (const float*)d_in[13];

    char* ws = (char*)d_ws;
    unsigned short* W16 = (unsigned short*)ws;              // 96 KB (pad to 128 KB)
    float* Wt  = (float*)(ws + 131072);                     // 768 KB
    float* Qh  = (float*)(ws + 131072 + 786432);            // 1 MB
    float* KVp = (float*)(ws + 131072 + 786432 + 1048576);  // 2 MB
    float* out = (float*)d_out;

    cvt_w_kernel<<<192, 256, 0, stream>>>(Weq, Wek, Wev, W16);
    trans_w_kernel<<<192, 256, 0, stream>>>(Wnq, Wnk, Wnv, Wt);
    qkv_kernel<<<768, 256, 0, stream>>>(node, Wt, bnq, bnk, bnv, beq, bek, bev, Qh, KVp);
    attn_kernel<<<256, 512, 0, stream>>>(edge, Qh, KVp, W16, out);
}

// Round 7
// 291.742 us; speedup vs baseline: 1.6230x; 1.6230x over previous
//
#include <hip/hip_runtime.h>

typedef __bf16 bf16x8 __attribute__((ext_vector_type(8)));
typedef float  f32x4  __attribute__((ext_vector_type(4)));
typedef unsigned int u32x4 __attribute__((ext_vector_type(4)));

#define B_   2
#define N_   512
#define ND_  256
#define ED_  64
#define NH_  8
#define DH_  32

// LDS row stride in shorts. 84 (not 72): a-frag reads hit banks
// (10*l15 + 4*q4) mod 32 -- all distinct -> SQ_LDS_BANK_CONFLICT == 0
// (measured round 5: 2,097,152 at stride 72 -> 0 at stride 84).
#define LROW 84

static __device__ __forceinline__ unsigned pack_bf16(float a, float b) {
    unsigned short ua = __builtin_bit_cast(unsigned short, (__bf16)a);
    unsigned short ub = __builtin_bit_cast(unsigned short, (__bf16)b);
    return (unsigned)ua | ((unsigned)ub << 16);
}

// ---------------- prep kernel 1: edge-weight fp32 -> bf16 (row-major [256][64])
__global__ __launch_bounds__(256) void cvt_w_kernel(
    const float* __restrict__ wq, const float* __restrict__ wk,
    const float* __restrict__ wv, unsigned short* __restrict__ w16)
{
    int id = blockIdx.x * 256 + threadIdx.x;          // 0..49151
    const float* src = (id < 16384) ? wq : (id < 32768 ? wk : wv);
    int idx = id & 16383;
    w16[id] = __builtin_bit_cast(unsigned short, (__bf16)src[idx]);
}

// ---------------- prep kernel 1b: transpose node weights -> Wt[m][k][c] fp32
__global__ __launch_bounds__(256) void trans_w_kernel(
    const float* __restrict__ Wq, const float* __restrict__ Wk,
    const float* __restrict__ Wv, float* __restrict__ Wt)
{
    __shared__ float t[32][33];
    const int bx = blockIdx.x;        // 0..191 = 3 mats * 64 tiles
    const int m  = bx >> 6;
    const int t6 = bx & 63;
    const int cb = (t6 >> 3) << 5;    // c-block
    const int kb = (t6 & 7) << 5;     // k-block
    const float* W = (m == 0) ? Wq : (m == 1 ? Wk : Wv);
    const int tx = threadIdx.x & 31, ty = threadIdx.x >> 5;   // 32 x 8
    #pragma unroll
    for (int s = 0; s < 4; s++)
        t[ty + 8 * s][tx] = W[(size_t)(cb + ty + 8 * s) * ND_ + kb + tx];
    __syncthreads();
    float* dst = Wt + (size_t)m * ND_ * ND_;
    #pragma unroll
    for (int s = 0; s < 4; s++)
        dst[(size_t)(kb + ty + 8 * s) * ND_ + cb + tx] = t[tx][ty + 8 * s];
}

// ------- prep kernel 2: node projections with coalesced (transposed) weights.
// Q -> row-major head-split Qh[bh][i][32].
// K,V -> KVp in MFMA C-fragment order so attn loads are lane-linear:
//   KVp float idx = ((bh*32 + j/16)*4 + set)*256 + (((d>>2)&3)*16 + (j&15))*4 + (d&3)
//   set: 0,1 = K halves (d<16 / d>=16), 2,3 = V halves.
__global__ __launch_bounds__(256) void qkv_kernel(
    const float* __restrict__ node, const float* __restrict__ Wt,
    const float* __restrict__ bnq, const float* __restrict__ bnk,
    const float* __restrict__ bnv, const float* __restrict__ beq,
    const float* __restrict__ bek, const float* __restrict__ bev,
    float* __restrict__ Qh, float* __restrict__ KVp)
{
    __shared__ float xs[4][ND_];
    const int c   = threadIdx.x;
    const int m   = blockIdx.x >> 8;       // 0=Q 1=K 2=V
    const int grp = blockIdx.x & 255;
    const int g0  = grp * 4;
    {
        const int r = c >> 6, col4 = (c & 63) * 4;
        const float4 v = *reinterpret_cast<const float4*>(node + (size_t)(g0 + r) * ND_ + col4);
        *reinterpret_cast<float4*>(&xs[r][col4]) = v;
    }
    __syncthreads();

    const float* Wm = Wt + (size_t)m * ND_ * ND_;
    float acc[4] = {0.f, 0.f, 0.f, 0.f};
    for (int k = 0; k < ND_; k += 4) {
        const float w0 = Wm[(size_t)(k + 0) * ND_ + c];
        const float w1 = Wm[(size_t)(k + 1) * ND_ + c];
        const float w2 = Wm[(size_t)(k + 2) * ND_ + c];
        const float w3 = Wm[(size_t)(k + 3) * ND_ + c];
        #pragma unroll
        for (int rr = 0; rr < 4; rr++) {
            const float4 x = *reinterpret_cast<const float4*>(&xs[rr][k]);
            acc[rr] += x.x * w0 + x.y * w1 + x.z * w2 + x.w * w3;
        }
    }
    const float bias = (m == 0) ? (bnq[c] + beq[c])
                     : (m == 1) ? (bnk[c] + bek[c])
                                : (bnv[c] + bev[c]);
    const int h = c >> 5, d = c & 31;
    #pragma unroll
    for (int rr = 0; rr < 4; rr++) {
        const int g  = g0 + rr;
        const int bb = g >> 9, ii = g & (N_ - 1);
        const int bh = bb * NH_ + h;
        const float y = acc[rr] + bias;
        if (m == 0) {
            Qh[((size_t)bh * N_ + ii) * DH_ + d] = y;
        } else {
            const int set = ((m == 1) ? 0 : 2) + (d >> 4);
            const size_t idx = (((size_t)bh * 32 + (ii >> 4)) * 4 + set) * 256
                             + (size_t)((((d >> 2) & 3) * 16 + (ii & 15)) * 4 + (d & 3));
            KVp[idx] = y;
        }
    }
}

// ---------------- main fused kernel: one block per (b, i-pair), 8 waves = 8 heads.
// EXACT round-1 structure (proven: 92 us, VGPR 124, zero scratch) plus two
// zero-register-cost fixes:
//   (1) LROW 72 -> 84: LDS bank conflicts 2.1M -> 0 (verified round 5);
//   (2) s_setprio(1/0) around the 12-MFMA cluster (T5, +4-7% on attn shapes).
// The 4-row variants (rounds 2-6) are dead: this toolchain hard-caps 512-thread
// kernels at 128 VGPRs (5 attribute configs all ignored), and 4-row demand
// ~190 regs can only exist as ~450 MB of scratch traffic.
__global__ __launch_bounds__(512, 2) void attn_kernel(
    const float* __restrict__ edge,
    const float* __restrict__ Qh, const float* __restrict__ KVp,
    const unsigned short* __restrict__ W16, float* __restrict__ out)
{
    __shared__ unsigned short lds_[2][2][64 * LROW];   // [buf][i-row][64 rows]

    const int tid  = threadIdx.x;
    const int lane = tid & 63;
    const int h    = tid >> 6;       // wave id == head
    const int q4   = lane >> 4;
    const int l15  = lane & 15;
    const int blk  = blockIdx.x;     // 0..511
    const int b    = blk >> 8;
    const int i0   = (blk & 255) * 2;
    const int bh   = b * NH_ + h;

    // W A-operand frags: A[m=l15][k=q4*8+kk]; wf[m][half][ks]
    bf16x8 wf[3][2][2];
    #pragma unroll
    for (int m = 0; m < 3; m++)
        #pragma unroll
        for (int hf = 0; hf < 2; hf++)
            #pragma unroll
            for (int ks = 0; ks < 2; ks++) {
                const u32x4* p = reinterpret_cast<const u32x4*>(
                    W16 + m * (ND_ * ED_) + (h * DH_ + hf * 16 + l15) * ED_ + ks * 32 + q4 * 8);
                wf[m][hf][ks] = __builtin_bit_cast(bf16x8, *p);
            }

    // Q C-init (row d = q4*4+r, broadcast over j=l15), for both i rows
    f32x4 Cq[2][2];
    {
        const float* Qrow = Qh + ((size_t)bh * N_ + i0) * DH_;
        Cq[0][0] = *reinterpret_cast<const f32x4*>(Qrow + q4 * 4);
        Cq[0][1] = *reinterpret_cast<const f32x4*>(Qrow + 16 + q4 * 4);
        Cq[1][0] = *reinterpret_cast<const f32x4*>(Qrow + DH_ + q4 * 4);
        Cq[1][1] = *reinterpret_cast<const f32x4*>(Qrow + DH_ + 16 + q4 * 4);
    }

    // lane-linear K/V fragment base: per jg, sets at +0,+64,+128,+192 (f32x4)
    const f32x4* kvb = reinterpret_cast<const f32x4*>(KVp + (size_t)bh * 32 * 1024) + lane;

    const float* eb0 = edge + ((size_t)(b * N_ + i0)) * N_ * ED_;
    const float* eb1 = eb0 + (size_t)N_ * ED_;

    float l_acc[2] = {0.f, 0.f};
    f32x4 o0[2] = {{0.f,0.f,0.f,0.f},{0.f,0.f,0.f,0.f}};
    f32x4 o1[2] = {{0.f,0.f,0.f,0.f},{0.f,0.f,0.f,0.f}};
    const float scale = 0.17677669529663687f;   // 1/sqrt(32)

    // stage chunk 0 for both i rows (each: 64 j-rows = 4096 floats)
    float4 g[2][2];
    {
        const float4* e0 = reinterpret_cast<const float4*>(eb0);
        const float4* e1 = reinterpret_cast<const float4*>(eb1);
        g[0][0] = e0[tid]; g[0][1] = e0[tid + 512];
        g[1][0] = e1[tid]; g[1][1] = e1[tid + 512];
    }
    #pragma unroll
    for (int ii = 0; ii < 2; ii++) {
        unsigned short* buf = lds_[0][ii];
        #pragma unroll
        for (int pt = 0; pt < 2; pt++) {
            const float4 gg = g[ii][pt];
            const int f = tid + pt * 512;
            const int row = f >> 4, c4 = f & 15;
            uint2 v = {pack_bf16(gg.x, gg.y), pack_bf16(gg.z, gg.w)};
            *reinterpret_cast<uint2*>(buf + row * LROW + c4 * 4) = v;
        }
    }
    // prefetch K/V for jg = 0
    f32x4 kn0 = kvb[0], kn1 = kvb[64], vn0 = kvb[128], vn1 = kvb[192];
    __syncthreads();

    #pragma unroll 1
    for (int ch = 0; ch < 8; ch++) {
        if (ch < 7) {   // issue next chunk's staging loads (consumed at chunk end)
            const float4* e0 = reinterpret_cast<const float4*>(eb0 + (ch + 1) * 4096);
            const float4* e1 = reinterpret_cast<const float4*>(eb1 + (ch + 1) * 4096);
            g[0][0] = e0[tid]; g[0][1] = e0[tid + 512];
            g[1][0] = e1[tid]; g[1][1] = e1[tid + 512];
        }
        const unsigned short* buf0 = lds_[ch & 1][0];
        const unsigned short* buf1 = lds_[ch & 1][1];

        #pragma unroll 2
        for (int sub = 0; sub < 4; sub++) {
            const int jg = ch * 4 + sub;
            // consume previously-prefetched K/V (older than staging loads above,
            // so this wait never drains them)
            const f32x4 Ck0 = kn0, Ck1 = kn1, Cv0 = vn0, Cv1 = vn1;
            {   // prefetch next jg (wraps harmlessly at the end)
                const f32x4* p = kvb + ((jg + 1) & 31) * 256;
                kn0 = p[0]; kn1 = p[64]; vn0 = p[128]; vn1 = p[192];
            }
            const unsigned short* ar0 = buf0 + (sub * 16 + l15) * LROW + q4 * 8;
            const unsigned short* ar1 = buf1 + (sub * 16 + l15) * LROW + q4 * 8;
            const bf16x8 a00 = __builtin_bit_cast(bf16x8, *reinterpret_cast<const u32x4*>(ar0));
            const bf16x8 a01 = __builtin_bit_cast(bf16x8, *reinterpret_cast<const u32x4*>(ar0 + 32));
            const bf16x8 a10 = __builtin_bit_cast(bf16x8, *reinterpret_cast<const u32x4*>(ar1));
            const bf16x8 a11 = __builtin_bit_cast(bf16x8, *reinterpret_cast<const u32x4*>(ar1 + 32));

            #pragma unroll
            for (int ii = 0; ii < 2; ii++) {
                const bf16x8 aA = ii ? a10 : a00;
                const bf16x8 aB = ii ? a11 : a01;
                __builtin_amdgcn_s_setprio(1);
                f32x4 eq0 = __builtin_amdgcn_mfma_f32_16x16x32_bf16(wf[0][0][0], aA, Cq[ii][0], 0, 0, 0);
                f32x4 eq1 = __builtin_amdgcn_mfma_f32_16x16x32_bf16(wf[0][1][0], aA, Cq[ii][1], 0, 0, 0);
                f32x4 ek0 = __builtin_amdgcn_mfma_f32_16x16x32_bf16(wf[1][0][0], aA, Ck0, 0, 0, 0);
                f32x4 ek1 = __builtin_amdgcn_mfma_f32_16x16x32_bf16(wf[1][1][0], aA, Ck1, 0, 0, 0);
                f32x4 ev0 = __builtin_amdgcn_mfma_f32_16x16x32_bf16(wf[2][0][0], aA, Cv0, 0, 0, 0);
                f32x4 ev1 = __builtin_amdgcn_mfma_f32_16x16x32_bf16(wf[2][1][0], aA, Cv1, 0, 0, 0);
                eq0 = __builtin_amdgcn_mfma_f32_16x16x32_bf16(wf[0][0][1], aB, eq0, 0, 0, 0);
                eq1 = __builtin_amdgcn_mfma_f32_16x16x32_bf16(wf[0][1][1], aB, eq1, 0, 0, 0);
                ek0 = __builtin_amdgcn_mfma_f32_16x16x32_bf16(wf[1][0][1], aB, ek0, 0, 0, 0);
                ek1 = __builtin_amdgcn_mfma_f32_16x16x32_bf16(wf[1][1][1], aB, ek1, 0, 0, 0);
                ev0 = __builtin_amdgcn_mfma_f32_16x16x32_bf16(wf[2][0][1], aB, ev0, 0, 0, 0);
                ev1 = __builtin_amdgcn_mfma_f32_16x16x32_bf16(wf[2][1][1], aB, ev1, 0, 0, 0);
                __builtin_amdgcn_s_setprio(0);

                // score for lane's j (quad-reduce over d), then unnormalized exp
                float ta = eq0[0]*ek0[0] + eq0[1]*ek0[1];
                float tb = eq0[2]*ek0[2] + eq0[3]*ek0[3];
                float tc = eq1[0]*ek1[0] + eq1[1]*ek1[1];
                float td = eq1[2]*ek1[2] + eq1[3]*ek1[3];
                float t = (ta + tb) + (tc + td);
                t += __shfl_xor(t, 16, 64);
                t += __shfl_xor(t, 32, 64);
                const float p = __expf(fmaf(t, scale, -4.f));   // shift cancels in norm

                l_acc[ii] += p;
                o0[ii] += ev0 * p;
                o1[ii] += ev1 * p;
            }
        }

        if (ch < 7) {   // pack+store next chunk into the other buffer
            #pragma unroll
            for (int ii = 0; ii < 2; ii++) {
                unsigned short* nbuf = lds_[(ch + 1) & 1][ii];
                #pragma unroll
                for (int pt = 0; pt < 2; pt++) {
                    const float4 gg = g[ii][pt];
                    const int f = tid + pt * 512;
                    const int row = f >> 4, c4 = f & 15;
                    uint2 v = {pack_bf16(gg.x, gg.y), pack_bf16(gg.z, gg.w)};
                    *reinterpret_cast<uint2*>(nbuf + row * LROW + c4 * 4) = v;
                }
            }
        }
        __syncthreads();
    }

    // final reductions over the 16 j-classes (l15)
    #pragma unroll
    for (int mask = 1; mask <= 8; mask <<= 1) {
        #pragma unroll
        for (int ii = 0; ii < 2; ii++) {
            l_acc[ii] += __shfl_xor(l_acc[ii], mask, 64);
            #pragma unroll
            for (int r = 0; r < 4; r++) {
                o0[ii][r] += __shfl_xor(o0[ii][r], mask, 64);
                o1[ii][r] += __shfl_xor(o1[ii][r], mask, 64);
            }
        }
    }
    if (l15 == 0) {
        #pragma unroll
        for (int ii = 0; ii < 2; ii++) {
            const float inv = 1.f / l_acc[ii];
            float* orow = out + ((size_t)(b * N_ + i0 + ii)) * ND_ + h * DH_ + q4 * 4;
            float4 va = {o0[ii][0] * inv, o0[ii][1] * inv, o0[ii][2] * inv, o0[ii][3] * inv};
            float4 vb = {o1[ii][0] * inv, o1[ii][1] * inv, o1[ii][2] * inv, o1[ii][3] * inv};
            *reinterpret_cast<float4*>(orow)      = va;
            *reinterpret_cast<float4*>(orow + 16) = vb;
        }
    }
}

extern "C" void kernel_launch(void* const* d_in, const int* in_sizes, int n_in,
                              void* d_out, int out_size, void* d_ws, size_t ws_size,
                              hipStream_t stream) {
    const float* node = (const float*)d_in[0];
    const float* edge = (const float*)d_in[1];
    const float* Wnq  = (const float*)d_in[2];
    const float* bnq  = (const float*)d_in[3];
    const float* Wnk  = (const float*)d_in[4];
    const float* bnk  = (const float*)d_in[5];
    const float* Wnv  = (const float*)d_in[6];
    const float* bnv  = (const float*)d_in[7];
    const float* Weq  = (const float*)d_in[8];
    const float* beq  = (const float*)d_in[9];
    const float* Wek  = (const float*)d_in[10];
    const float* bek  = (const float*)d_in[11];
    const float* Wev  = (const float*)d_in[12];
    const float* bev  = (const float*)d_in[13];

    char* ws = (char*)d_ws;
    unsigned short* W16 = (unsigned short*)ws;              // 96 KB (pad to 128 KB)
    float* Wt  = (float*)(ws + 131072);                     // 768 KB
    float* Qh  = (float*)(ws + 131072 + 786432);            // 1 MB
    float* KVp = (float*)(ws + 131072 + 786432 + 1048576);  // 2 MB
    float* out = (float*)d_out;

    cvt_w_kernel<<<192, 256, 0, stream>>>(Weq, Wek, Wev, W16);
    trans_w_kernel<<<192, 256, 0, stream>>>(Wnq, Wnk, Wnv, Wt);
    qkv_kernel<<<768, 256, 0, stream>>>(node, Wt, bnq, bnk, bnv, beq, bek, bev, Qh, KVp);
    attn_kernel<<<512, 512, 0, stream>>>(edge, Qh, KVp, W16, out);
}

// Round 8
// 288.318 us; speedup vs baseline: 1.6422x; 1.0119x over previous
//
#include <hip/hip_runtime.h>

typedef __bf16 bf16x8 __attribute__((ext_vector_type(8)));
typedef float  f32x4  __attribute__((ext_vector_type(4)));
typedef unsigned int u32x4 __attribute__((ext_vector_type(4)));

#define B_   2
#define N_   512
#define ND_  256
#define ED_  64
#define NH_  8
#define DH_  32

// LDS row stride in shorts. 84: SQ_LDS_BANK_CONFLICT == 0 measured (round 5/7)
// vs 2.1M at 72. Round 8 isolates setprio-removal with LROW held at 84.
#define LROW 84

static __device__ __forceinline__ unsigned pack_bf16(float a, float b) {
    unsigned short ua = __builtin_bit_cast(unsigned short, (__bf16)a);
    unsigned short ub = __builtin_bit_cast(unsigned short, (__bf16)b);
    return (unsigned)ua | ((unsigned)ub << 16);
}

// ---------------- prep kernel 1: edge-weight fp32 -> bf16 (row-major [256][64])
__global__ __launch_bounds__(256) void cvt_w_kernel(
    const float* __restrict__ wq, const float* __restrict__ wk,
    const float* __restrict__ wv, unsigned short* __restrict__ w16)
{
    int id = blockIdx.x * 256 + threadIdx.x;          // 0..49151
    const float* src = (id < 16384) ? wq : (id < 32768 ? wk : wv);
    int idx = id & 16383;
    w16[id] = __builtin_bit_cast(unsigned short, (__bf16)src[idx]);
}

// ---------------- prep kernel 1b: transpose node weights -> Wt[m][k][c] fp32
__global__ __launch_bounds__(256) void trans_w_kernel(
    const float* __restrict__ Wq, const float* __restrict__ Wk,
    const float* __restrict__ Wv, float* __restrict__ Wt)
{
    __shared__ float t[32][33];
    const int bx = blockIdx.x;        // 0..191 = 3 mats * 64 tiles
    const int m  = bx >> 6;
    const int t6 = bx & 63;
    const int cb = (t6 >> 3) << 5;    // c-block
    const int kb = (t6 & 7) << 5;     // k-block
    const float* W = (m == 0) ? Wq : (m == 1 ? Wk : Wv);
    const int tx = threadIdx.x & 31, ty = threadIdx.x >> 5;   // 32 x 8
    #pragma unroll
    for (int s = 0; s < 4; s++)
        t[ty + 8 * s][tx] = W[(size_t)(cb + ty + 8 * s) * ND_ + kb + tx];
    __syncthreads();
    float* dst = Wt + (size_t)m * ND_ * ND_;
    #pragma unroll
    for (int s = 0; s < 4; s++)
        dst[(size_t)(kb + ty + 8 * s) * ND_ + cb + tx] = t[tx][ty + 8 * s];
}

// ------- prep kernel 2: node projections with coalesced (transposed) weights.
// Q -> row-major head-split Qh[bh][i][32].
// K,V -> KVp in MFMA C-fragment order so attn loads are lane-linear:
//   KVp float idx = ((bh*32 + j/16)*4 + set)*256 + (((d>>2)&3)*16 + (j&15))*4 + (d&3)
//   set: 0,1 = K halves (d<16 / d>=16), 2,3 = V halves.
__global__ __launch_bounds__(256) void qkv_kernel(
    const float* __restrict__ node, const float* __restrict__ Wt,
    const float* __restrict__ bnq, const float* __restrict__ bnk,
    const float* __restrict__ bnv, const float* __restrict__ beq,
    const float* __restrict__ bek, const float* __restrict__ bev,
    float* __restrict__ Qh, float* __restrict__ KVp)
{
    __shared__ float xs[4][ND_];
    const int c   = threadIdx.x;
    const int m   = blockIdx.x >> 8;       // 0=Q 1=K 2=V
    const int grp = blockIdx.x & 255;
    const int g0  = grp * 4;
    {
        const int r = c >> 6, col4 = (c & 63) * 4;
        const float4 v = *reinterpret_cast<const float4*>(node + (size_t)(g0 + r) * ND_ + col4);
        *reinterpret_cast<float4*>(&xs[r][col4]) = v;
    }
    __syncthreads();

    const float* Wm = Wt + (size_t)m * ND_ * ND_;
    float acc[4] = {0.f, 0.f, 0.f, 0.f};
    for (int k = 0; k < ND_; k += 4) {
        const float w0 = Wm[(size_t)(k + 0) * ND_ + c];
        const float w1 = Wm[(size_t)(k + 1) * ND_ + c];
        const float w2 = Wm[(size_t)(k + 2) * ND_ + c];
        const float w3 = Wm[(size_t)(k + 3) * ND_ + c];
        #pragma unroll
        for (int rr = 0; rr < 4; rr++) {
            const float4 x = *reinterpret_cast<const float4*>(&xs[rr][k]);
            acc[rr] += x.x * w0 + x.y * w1 + x.z * w2 + x.w * w3;
        }
    }
    const float bias = (m == 0) ? (bnq[c] + beq[c])
                     : (m == 1) ? (bnk[c] + bek[c])
                                : (bnv[c] + bev[c]);
    const int h = c >> 5, d = c & 31;
    #pragma unroll
    for (int rr = 0; rr < 4; rr++) {
        const int g  = g0 + rr;
        const int bb = g >> 9, ii = g & (N_ - 1);
        const int bh = bb * NH_ + h;
        const float y = acc[rr] + bias;
        if (m == 0) {
            Qh[((size_t)bh * N_ + ii) * DH_ + d] = y;
        } else {
            const int set = ((m == 1) ? 0 : 2) + (d >> 4);
            const size_t idx = (((size_t)bh * 32 + (ii >> 4)) * 4 + set) * 256
                             + (size_t)((((d >> 2) & 3) * 16 + (ii & 15)) * 4 + (d & 3));
            KVp[idx] = y;
        }
    }
}

// ---------------- main fused kernel: one block per (b, i-pair), 8 waves = 8 heads.
// Round-1 structure (proven 92 us, VGPR 124, zero scratch) + LROW 84.
// NO s_setprio: round 7 showed it acts as a scheduling fence on this
// barrier-synced 8-wave block (VGPR 124->96, MfmaUtil 23->18, dur 92->116);
// matches m190 (setprio hurts lockstep structures; m191's +7% was on
// independent 1-wave blocks).
__global__ __launch_bounds__(512, 2) void attn_kernel(
    const float* __restrict__ edge,
    const float* __restrict__ Qh, const float* __restrict__ KVp,
    const unsigned short* __restrict__ W16, float* __restrict__ out)
{
    __shared__ unsigned short lds_[2][2][64 * LROW];   // [buf][i-row][64 rows]

    const int tid  = threadIdx.x;
    const int lane = tid & 63;
    const int h    = tid >> 6;       // wave id == head
    const int q4   = lane >> 4;
    const int l15  = lane & 15;
    const int blk  = blockIdx.x;     // 0..511
    const int b    = blk >> 8;
    const int i0   = (blk & 255) * 2;
    const int bh   = b * NH_ + h;

    // W A-operand frags: A[m=l15][k=q4*8+kk]; wf[m][half][ks]
    bf16x8 wf[3][2][2];
    #pragma unroll
    for (int m = 0; m < 3; m++)
        #pragma unroll
        for (int hf = 0; hf < 2; hf++)
            #pragma unroll
            for (int ks = 0; ks < 2; ks++) {
                const u32x4* p = reinterpret_cast<const u32x4*>(
                    W16 + m * (ND_ * ED_) + (h * DH_ + hf * 16 + l15) * ED_ + ks * 32 + q4 * 8);
                wf[m][hf][ks] = __builtin_bit_cast(bf16x8, *p);
            }

    // Q C-init (row d = q4*4+r, broadcast over j=l15), for both i rows
    f32x4 Cq[2][2];
    {
        const float* Qrow = Qh + ((size_t)bh * N_ + i0) * DH_;
        Cq[0][0] = *reinterpret_cast<const f32x4*>(Qrow + q4 * 4);
        Cq[0][1] = *reinterpret_cast<const f32x4*>(Qrow + 16 + q4 * 4);
        Cq[1][0] = *reinterpret_cast<const f32x4*>(Qrow + DH_ + q4 * 4);
        Cq[1][1] = *reinterpret_cast<const f32x4*>(Qrow + DH_ + 16 + q4 * 4);
    }

    // lane-linear K/V fragment base: per jg, sets at +0,+64,+128,+192 (f32x4)
    const f32x4* kvb = reinterpret_cast<const f32x4*>(KVp + (size_t)bh * 32 * 1024) + lane;

    const float* eb0 = edge + ((size_t)(b * N_ + i0)) * N_ * ED_;
    const float* eb1 = eb0 + (size_t)N_ * ED_;

    float l_acc[2] = {0.f, 0.f};
    f32x4 o0[2] = {{0.f,0.f,0.f,0.f},{0.f,0.f,0.f,0.f}};
    f32x4 o1[2] = {{0.f,0.f,0.f,0.f},{0.f,0.f,0.f,0.f}};
    const float scale = 0.17677669529663687f;   // 1/sqrt(32)

    // stage chunk 0 for both i rows (each: 64 j-rows = 4096 floats)
    float4 g[2][2];
    {
        const float4* e0 = reinterpret_cast<const float4*>(eb0);
        const float4* e1 = reinterpret_cast<const float4*>(eb1);
        g[0][0] = e0[tid]; g[0][1] = e0[tid + 512];
        g[1][0] = e1[tid]; g[1][1] = e1[tid + 512];
    }
    #pragma unroll
    for (int ii = 0; ii < 2; ii++) {
        unsigned short* buf = lds_[0][ii];
        #pragma unroll
        for (int pt = 0; pt < 2; pt++) {
            const float4 gg = g[ii][pt];
            const int f = tid + pt * 512;
            const int row = f >> 4, c4 = f & 15;
            uint2 v = {pack_bf16(gg.x, gg.y), pack_bf16(gg.z, gg.w)};
            *reinterpret_cast<uint2*>(buf + row * LROW + c4 * 4) = v;
        }
    }
    // prefetch K/V for jg = 0
    f32x4 kn0 = kvb[0], kn1 = kvb[64], vn0 = kvb[128], vn1 = kvb[192];
    __syncthreads();

    #pragma unroll 1
    for (int ch = 0; ch < 8; ch++) {
        if (ch < 7) {   // issue next chunk's staging loads (consumed at chunk end)
            const float4* e0 = reinterpret_cast<const float4*>(eb0 + (ch + 1) * 4096);
            const float4* e1 = reinterpret_cast<const float4*>(eb1 + (ch + 1) * 4096);
            g[0][0] = e0[tid]; g[0][1] = e0[tid + 512];
            g[1][0] = e1[tid]; g[1][1] = e1[tid + 512];
        }
        const unsigned short* buf0 = lds_[ch & 1][0];
        const unsigned short* buf1 = lds_[ch & 1][1];

        #pragma unroll 2
        for (int sub = 0; sub < 4; sub++) {
            const int jg = ch * 4 + sub;
            // consume previously-prefetched K/V (older than staging loads above,
            // so this wait never drains them)
            const f32x4 Ck0 = kn0, Ck1 = kn1, Cv0 = vn0, Cv1 = vn1;
            {   // prefetch next jg (wraps harmlessly at the end)
                const f32x4* p = kvb + ((jg + 1) & 31) * 256;
                kn0 = p[0]; kn1 = p[64]; vn0 = p[128]; vn1 = p[192];
            }
            const unsigned short* ar0 = buf0 + (sub * 16 + l15) * LROW + q4 * 8;
            const unsigned short* ar1 = buf1 + (sub * 16 + l15) * LROW + q4 * 8;
            const bf16x8 a00 = __builtin_bit_cast(bf16x8, *reinterpret_cast<const u32x4*>(ar0));
            const bf16x8 a01 = __builtin_bit_cast(bf16x8, *reinterpret_cast<const u32x4*>(ar0 + 32));
            const bf16x8 a10 = __builtin_bit_cast(bf16x8, *reinterpret_cast<const u32x4*>(ar1));
            const bf16x8 a11 = __builtin_bit_cast(bf16x8, *reinterpret_cast<const u32x4*>(ar1 + 32));

            #pragma unroll
            for (int ii = 0; ii < 2; ii++) {
                const bf16x8 aA = ii ? a10 : a00;
                const bf16x8 aB = ii ? a11 : a01;
                f32x4 eq0 = __builtin_amdgcn_mfma_f32_16x16x32_bf16(wf[0][0][0], aA, Cq[ii][0], 0, 0, 0);
                f32x4 eq1 = __builtin_amdgcn_mfma_f32_16x16x32_bf16(wf[0][1][0], aA, Cq[ii][1], 0, 0, 0);
                f32x4 ek0 = __builtin_amdgcn_mfma_f32_16x16x32_bf16(wf[1][0][0], aA, Ck0, 0, 0, 0);
                f32x4 ek1 = __builtin_amdgcn_mfma_f32_16x16x32_bf16(wf[1][1][0], aA, Ck1, 0, 0, 0);
                f32x4 ev0 = __builtin_amdgcn_mfma_f32_16x16x32_bf16(wf[2][0][0], aA, Cv0, 0, 0, 0);
                f32x4 ev1 = __builtin_amdgcn_mfma_f32_16x16x32_bf16(wf[2][1][0], aA, Cv1, 0, 0, 0);
                eq0 = __builtin_amdgcn_mfma_f32_16x16x32_bf16(wf[0][0][1], aB, eq0, 0, 0, 0);
                eq1 = __builtin_amdgcn_mfma_f32_16x16x32_bf16(wf[0][1][1], aB, eq1, 0, 0, 0);
                ek0 = __builtin_amdgcn_mfma_f32_16x16x32_bf16(wf[1][0][1], aB, ek0, 0, 0, 0);
                ek1 = __builtin_amdgcn_mfma_f32_16x16x32_bf16(wf[1][1][1], aB, ek1, 0, 0, 0);
                ev0 = __builtin_amdgcn_mfma_f32_16x16x32_bf16(wf[2][0][1], aB, ev0, 0, 0, 0);
                ev1 = __builtin_amdgcn_mfma_f32_16x16x32_bf16(wf[2][1][1], aB, ev1, 0, 0, 0);

                // score for lane's j (quad-reduce over d), then unnormalized exp
                float ta = eq0[0]*ek0[0] + eq0[1]*ek0[1];
                float tb = eq0[2]*ek0[2] + eq0[3]*ek0[3];
                float tc = eq1[0]*ek1[0] + eq1[1]*ek1[1];
                float td = eq1[2]*ek1[2] + eq1[3]*ek1[3];
                float t = (ta + tb) + (tc + td);
                t += __shfl_xor(t, 16, 64);
                t += __shfl_xor(t, 32, 64);
                const float p = __expf(fmaf(t, scale, -4.f));   // shift cancels in norm

                l_acc[ii] += p;
                o0[ii] += ev0 * p;
                o1[ii] += ev1 * p;
            }
        }

        if (ch < 7) {   // pack+store next chunk into the other buffer
            #pragma unroll
            for (int ii = 0; ii < 2; ii++) {
                unsigned short* nbuf = lds_[(ch + 1) & 1][ii];
                #pragma unroll
                for (int pt = 0; pt < 2; pt++) {
                    const float4 gg = g[ii][pt];
                    const int f = tid + pt * 512;
                    const int row = f >> 4, c4 = f & 15;
                    uint2 v = {pack_bf16(gg.x, gg.y), pack_bf16(gg.z, gg.w)};
                    *reinterpret_cast<uint2*>(nbuf + row * LROW + c4 * 4) = v;
                }
            }
        }
        __syncthreads();
    }

    // final reductions over the 16 j-classes (l15)
    #pragma unroll
    for (int mask = 1; mask <= 8; mask <<= 1) {
        #pragma unroll
        for (int ii = 0; ii < 2; ii++) {
            l_acc[ii] += __shfl_xor(l_acc[ii], mask, 64);
            #pragma unroll
            for (int r = 0; r < 4; r++) {
                o0[ii][r] += __shfl_xor(o0[ii][r], mask, 64);
                o1[ii][r] += __shfl_xor(o1[ii][r], mask, 64);
            }
        }
    }
    if (l15 == 0) {
        #pragma unroll
        for (int ii = 0; ii < 2; ii++) {
            const float inv = 1.f / l_acc[ii];
            float* orow = out + ((size_t)(b * N_ + i0 + ii)) * ND_ + h * DH_ + q4 * 4;
            float4 va = {o0[ii][0] * inv, o0[ii][1] * inv, o0[ii][2] * inv, o0[ii][3] * inv};
            float4 vb = {o1[ii][0] * inv, o1[ii][1] * inv, o1[ii][2] * inv, o1[ii][3] * inv};
            *reinterpret_cast<float4*>(orow)      = va;
            *reinterpret_cast<float4*>(orow + 16) = vb;
        }
    }
}

extern "C" void kernel_launch(void* const* d_in, const int* in_sizes, int n_in,
                              void* d_out, int out_size, void* d_ws, size_t ws_size,
                              hipStream_t stream) {
    const float* node = (const float*)d_in[0];
    const float* edge = (const float*)d_in[1];
    const float* Wnq  = (const float*)d_in[2];
    const float* bnq  = (const float*)d_in[3];
    const float* Wnk  = (const float*)d_in[4];
    const float* bnk  = (const float*)d_in[5];
    const float* Wnv  = (const float*)d_in[6];
    const float* bnv  = (const float*)d_in[7];
    const float* Weq  = (const float*)d_in[8];
    const float* beq  = (const float*)d_in[9];
    const float* Wek  = (const float*)d_in[10];
    const float* bek  = (const float*)d_in[11];
    const float* Wev  = (const float*)d_in[12];
    const float* bev  = (const float*)d_in[13];

    char* ws = (char*)d_ws;
    unsigned short* W16 = (unsigned short*)ws;              // 96 KB (pad to 128 KB)
    float* Wt  = (float*)(ws + 131072);                     // 768 KB
    float* Qh  = (float*)(ws + 131072 + 786432);            // 1 MB
    float* KVp = (float*)(ws + 131072 + 786432 + 1048576);  // 2 MB
    float* out = (float*)d_out;

    cvt_w_kernel<<<192, 256, 0, stream>>>(Weq, Wek, Wev, W16);
    trans_w_kernel<<<192, 256, 0, stream>>>(Wnq, Wnk, Wnv, Wt);
    qkv_kernel<<<768, 256, 0, stream>>>(node, Wt, bnq, bnk, bnv, beq, bek, bev, Qh, KVp);
    attn_kernel<<<512, 512, 0, stream>>>(edge, Qh, KVp, W16, out);
}

// Round 9
// 272.564 us; speedup vs baseline: 1.7371x; 1.0578x over previous
//
#include <hip/hip_runtime.h>

typedef __bf16 bf16x8 __attribute__((ext_vector_type(8)));
typedef float  f32x4  __attribute__((ext_vector_type(4)));
typedef unsigned int u32x4 __attribute__((ext_vector_type(4)));

#define B_   2
#define N_   512
#define ND_  256
#define ED_  64
#define NH_  8
#define DH_  32

static __device__ __forceinline__ unsigned pack_bf16(float a, float b) {
    unsigned short ua = __builtin_bit_cast(unsigned short, (__bf16)a);
    unsigned short ub = __builtin_bit_cast(unsigned short, (__bf16)b);
    return (unsigned)ua | ((unsigned)ub << 16);
}

// ---------------- prep kernel 1: edge-weight fp32 -> bf16 (row-major [256][64])
__global__ __launch_bounds__(256) void cvt_w_kernel(
    const float* __restrict__ wq, const float* __restrict__ wk,
    const float* __restrict__ wv, unsigned short* __restrict__ w16)
{
    int id = blockIdx.x * 256 + threadIdx.x;          // 0..49151
    const float* src = (id < 16384) ? wq : (id < 32768 ? wk : wv);
    int idx = id & 16383;
    w16[id] = __builtin_bit_cast(unsigned short, (__bf16)src[idx]);
}

// ---------------- prep kernel 1b: transpose node weights -> Wt[m][k][c] fp32
__global__ __launch_bounds__(256) void trans_w_kernel(
    const float* __restrict__ Wq, const float* __restrict__ Wk,
    const float* __restrict__ Wv, float* __restrict__ Wt)
{
    __shared__ float t[32][33];
    const int bx = blockIdx.x;        // 0..191 = 3 mats * 64 tiles
    const int m  = bx >> 6;
    const int t6 = bx & 63;
    const int cb = (t6 >> 3) << 5;    // c-block
    const int kb = (t6 & 7) << 5;     // k-block
    const float* W = (m == 0) ? Wq : (m == 1 ? Wk : Wv);
    const int tx = threadIdx.x & 31, ty = threadIdx.x >> 5;   // 32 x 8
    #pragma unroll
    for (int s = 0; s < 4; s++)
        t[ty + 8 * s][tx] = W[(size_t)(cb + ty + 8 * s) * ND_ + kb + tx];
    __syncthreads();
    float* dst = Wt + (size_t)m * ND_ * ND_;
    #pragma unroll
    for (int s = 0; s < 4; s++)
        dst[(size_t)(kb + ty + 8 * s) * ND_ + cb + tx] = t[tx][ty + 8 * s];
}

// ------- prep kernel 2: node projections with coalesced (transposed) weights.
// 8 output rows per block (was 4): halves the per-block weight-panel re-read
// traffic (196 MB -> 98 MB aggregate). Q -> row-major head-split Qh[bh][i][32].
// K,V -> KVp in MFMA C-fragment order so attn loads are lane-linear:
//   KVp float idx = ((bh*32 + j/16)*4 + set)*256 + (((d>>2)&3)*16 + (j&15))*4 + (d&3)
//   set: 0,1 = K halves (d<16 / d>=16), 2,3 = V halves.
__global__ __launch_bounds__(256) void qkv_kernel(
    const float* __restrict__ node, const float* __restrict__ Wt,
    const float* __restrict__ bnq, const float* __restrict__ bnk,
    const float* __restrict__ bnv, const float* __restrict__ beq,
    const float* __restrict__ bek, const float* __restrict__ bev,
    float* __restrict__ Qh, float* __restrict__ KVp)
{
    __shared__ float xs[8][ND_];
    const int c   = threadIdx.x;
    const int m   = blockIdx.x >> 7;       // 384 blocks: 0=Q 1=K 2=V
    const int grp = blockIdx.x & 127;
    const int g0  = grp * 8;
    #pragma unroll
    for (int s = 0; s < 2; s++) {
        const int f = s * 256 + c;               // float4 index 0..511
        const int r = f >> 6, col4 = (f & 63) * 4;
        const float4 v = *reinterpret_cast<const float4*>(node + (size_t)(g0 + r) * ND_ + col4);
        *reinterpret_cast<float4*>(&xs[r][col4]) = v;
    }
    __syncthreads();

    const float* Wm = Wt + (size_t)m * ND_ * ND_;
    float acc[8] = {};
    for (int k = 0; k < ND_; k += 4) {
        const float w0 = Wm[(size_t)(k + 0) * ND_ + c];
        const float w1 = Wm[(size_t)(k + 1) * ND_ + c];
        const float w2 = Wm[(size_t)(k + 2) * ND_ + c];
        const float w3 = Wm[(size_t)(k + 3) * ND_ + c];
        #pragma unroll
        for (int rr = 0; rr < 8; rr++) {
            const float4 x = *reinterpret_cast<const float4*>(&xs[rr][k]);
            acc[rr] += x.x * w0 + x.y * w1 + x.z * w2 + x.w * w3;
        }
    }
    const float bias = (m == 0) ? (bnq[c] + beq[c])
                     : (m == 1) ? (bnk[c] + bek[c])
                                : (bnv[c] + bev[c]);
    const int h = c >> 5, d = c & 31;
    #pragma unroll
    for (int rr = 0; rr < 8; rr++) {
        const int g  = g0 + rr;
        const int bb = g >> 9, ii = g & (N_ - 1);
        const int bh = bb * NH_ + h;
        const float y = acc[rr] + bias;
        if (m == 0) {
            Qh[((size_t)bh * N_ + ii) * DH_ + d] = y;
        } else {
            const int set = ((m == 1) ? 0 : 2) + (d >> 4);
            const size_t idx = (((size_t)bh * 32 + (ii >> 4)) * 4 + set) * 256
                             + (size_t)((((d >> 2) & 3) * 16 + (ii & 15)) * 4 + (d & 3));
            KVp[idx] = y;
        }
    }
}

// ---------------- main fused kernel: EXACT round-1 state (measured 92 us,
// VGPR 124, zero scratch). Stride 72 (16B-aligned rows -> ds_read_b128 intact;
// the 2.1M bank conflicts are ~2-way and ~free, m136). No s_setprio (acts as
// a scheduling fence here: r7 showed VGPR 124->96, dur +24 us). LROW 84 also
// dead: 168B rows break b128 alignment (r8: +19 us vs r1).
__global__ __launch_bounds__(512, 2) void attn_kernel(
    const float* __restrict__ edge,
    const float* __restrict__ Qh, const float* __restrict__ KVp,
    const unsigned short* __restrict__ W16, float* __restrict__ out)
{
    __shared__ unsigned short lds_[2][2][64 * 72];   // [buf][i-row][64 rows * 72]

    const int tid  = threadIdx.x;
    const int lane = tid & 63;
    const int h    = tid >> 6;       // wave id == head
    const int q4   = lane >> 4;
    const int l15  = lane & 15;
    const int blk  = blockIdx.x;     // 0..511
    const int b    = blk >> 8;
    const int i0   = (blk & 255) * 2;
    const int bh   = b * NH_ + h;

    // W A-operand frags: A[m=l15][k=q4*8+kk]; wf[m][half][ks]
    bf16x8 wf[3][2][2];
    #pragma unroll
    for (int m = 0; m < 3; m++)
        #pragma unroll
        for (int hf = 0; hf < 2; hf++)
            #pragma unroll
            for (int ks = 0; ks < 2; ks++) {
                const u32x4* p = reinterpret_cast<const u32x4*>(
                    W16 + m * (ND_ * ED_) + (h * DH_ + hf * 16 + l15) * ED_ + ks * 32 + q4 * 8);
                wf[m][hf][ks] = __builtin_bit_cast(bf16x8, *p);
            }

    // Q C-init (row d = q4*4+r, broadcast over j=l15), for both i rows
    f32x4 Cq[2][2];
    {
        const float* Qrow = Qh + ((size_t)bh * N_ + i0) * DH_;
        Cq[0][0] = *reinterpret_cast<const f32x4*>(Qrow + q4 * 4);
        Cq[0][1] = *reinterpret_cast<const f32x4*>(Qrow + 16 + q4 * 4);
        Cq[1][0] = *reinterpret_cast<const f32x4*>(Qrow + DH_ + q4 * 4);
        Cq[1][1] = *reinterpret_cast<const f32x4*>(Qrow + DH_ + 16 + q4 * 4);
    }

    // lane-linear K/V fragment base: per jg, sets at +0,+64,+128,+192 (f32x4)
    const f32x4* kvb = reinterpret_cast<const f32x4*>(KVp + (size_t)bh * 32 * 1024) + lane;

    const float* eb0 = edge + ((size_t)(b * N_ + i0)) * N_ * ED_;
    const float* eb1 = eb0 + (size_t)N_ * ED_;

    float l_acc[2] = {0.f, 0.f};
    f32x4 o0[2] = {{0.f,0.f,0.f,0.f},{0.f,0.f,0.f,0.f}};
    f32x4 o1[2] = {{0.f,0.f,0.f,0.f},{0.f,0.f,0.f,0.f}};
    const float scale = 0.17677669529663687f;   // 1/sqrt(32)

    // stage chunk 0 for both i rows (each: 64 j-rows = 4096 floats)
    float4 g[2][2];
    {
        const float4* e0 = reinterpret_cast<const float4*>(eb0);
        const float4* e1 = reinterpret_cast<const float4*>(eb1);
        g[0][0] = e0[tid]; g[0][1] = e0[tid + 512];
        g[1][0] = e1[tid]; g[1][1] = e1[tid + 512];
    }
    #pragma unroll
    for (int ii = 0; ii < 2; ii++) {
        unsigned short* buf = lds_[0][ii];
        #pragma unroll
        for (int pt = 0; pt < 2; pt++) {
            const float4 gg = g[ii][pt];
            const int f = tid + pt * 512;
            const int row = f >> 4, c4 = f & 15;
            uint2 v = {pack_bf16(gg.x, gg.y), pack_bf16(gg.z, gg.w)};
            *reinterpret_cast<uint2*>(buf + row * 72 + c4 * 4) = v;
        }
    }
    // prefetch K/V for jg = 0
    f32x4 kn0 = kvb[0], kn1 = kvb[64], vn0 = kvb[128], vn1 = kvb[192];
    __syncthreads();

    #pragma unroll 1
    for (int ch = 0; ch < 8; ch++) {
        if (ch < 7) {   // issue next chunk's staging loads (consumed at chunk end)
            const float4* e0 = reinterpret_cast<const float4*>(eb0 + (ch + 1) * 4096);
            const float4* e1 = reinterpret_cast<const float4*>(eb1 + (ch + 1) * 4096);
            g[0][0] = e0[tid]; g[0][1] = e0[tid + 512];
            g[1][0] = e1[tid]; g[1][1] = e1[tid + 512];
        }
        const unsigned short* buf0 = lds_[ch & 1][0];
        const unsigned short* buf1 = lds_[ch & 1][1];

        #pragma unroll 2
        for (int sub = 0; sub < 4; sub++) {
            const int jg = ch * 4 + sub;
            // consume previously-prefetched K/V (oldest outstanding vmem group)
            const f32x4 Ck0 = kn0, Ck1 = kn1, Cv0 = vn0, Cv1 = vn1;
            {   // prefetch next jg (wraps harmlessly at the end)
                const f32x4* p = kvb + ((jg + 1) & 31) * 256;
                kn0 = p[0]; kn1 = p[64]; vn0 = p[128]; vn1 = p[192];
            }
            const unsigned short* ar0 = buf0 + (sub * 16 + l15) * 72 + q4 * 8;
            const unsigned short* ar1 = buf1 + (sub * 16 + l15) * 72 + q4 * 8;
            const bf16x8 a00 = __builtin_bit_cast(bf16x8, *reinterpret_cast<const u32x4*>(ar0));
            const bf16x8 a01 = __builtin_bit_cast(bf16x8, *reinterpret_cast<const u32x4*>(ar0 + 32));
            const bf16x8 a10 = __builtin_bit_cast(bf16x8, *reinterpret_cast<const u32x4*>(ar1));
            const bf16x8 a11 = __builtin_bit_cast(bf16x8, *reinterpret_cast<const u32x4*>(ar1 + 32));

            #pragma unroll
            for (int ii = 0; ii < 2; ii++) {
                const bf16x8 aA = ii ? a10 : a00;
                const bf16x8 aB = ii ? a11 : a01;
                f32x4 eq0 = __builtin_amdgcn_mfma_f32_16x16x32_bf16(wf[0][0][0], aA, Cq[ii][0], 0, 0, 0);
                f32x4 eq1 = __builtin_amdgcn_mfma_f32_16x16x32_bf16(wf[0][1][0], aA, Cq[ii][1], 0, 0, 0);
                f32x4 ek0 = __builtin_amdgcn_mfma_f32_16x16x32_bf16(wf[1][0][0], aA, Ck0, 0, 0, 0);
                f32x4 ek1 = __builtin_amdgcn_mfma_f32_16x16x32_bf16(wf[1][1][0], aA, Ck1, 0, 0, 0);
                f32x4 ev0 = __builtin_amdgcn_mfma_f32_16x16x32_bf16(wf[2][0][0], aA, Cv0, 0, 0, 0);
                f32x4 ev1 = __builtin_amdgcn_mfma_f32_16x16x32_bf16(wf[2][1][0], aA, Cv1, 0, 0, 0);
                eq0 = __builtin_amdgcn_mfma_f32_16x16x32_bf16(wf[0][0][1], aB, eq0, 0, 0, 0);
                eq1 = __builtin_amdgcn_mfma_f32_16x16x32_bf16(wf[0][1][1], aB, eq1, 0, 0, 0);
                ek0 = __builtin_amdgcn_mfma_f32_16x16x32_bf16(wf[1][0][1], aB, ek0, 0, 0, 0);
                ek1 = __builtin_amdgcn_mfma_f32_16x16x32_bf16(wf[1][1][1], aB, ek1, 0, 0, 0);
                ev0 = __builtin_amdgcn_mfma_f32_16x16x32_bf16(wf[2][0][1], aB, ev0, 0, 0, 0);
                ev1 = __builtin_amdgcn_mfma_f32_16x16x32_bf16(wf[2][1][1], aB, ev1, 0, 0, 0);

                // score for lane's j (quad-reduce over d), then unnormalized exp
                float ta = eq0[0]*ek0[0] + eq0[1]*ek0[1];
                float tb = eq0[2]*ek0[2] + eq0[3]*ek0[3];
                float tc = eq1[0]*ek1[0] + eq1[1]*ek1[1];
                float td = eq1[2]*ek1[2] + eq1[3]*ek1[3];
                float t = (ta + tb) + (tc + td);
                t += __shfl_xor(t, 16, 64);
                t += __shfl_xor(t, 32, 64);
                const float p = __expf(fmaf(t, scale, -4.f));   // shift cancels in norm

                l_acc[ii] += p;
                o0[ii] += ev0 * p;
                o1[ii] += ev1 * p;
            }
        }

        if (ch < 7) {   // pack+store next chunk into the other buffer
            #pragma unroll
            for (int ii = 0; ii < 2; ii++) {
                unsigned short* nbuf = lds_[(ch + 1) & 1][ii];
                #pragma unroll
                for (int pt = 0; pt < 2; pt++) {
                    const float4 gg = g[ii][pt];
                    const int f = tid + pt * 512;
                    const int row = f >> 4, c4 = f & 15;
                    uint2 v = {pack_bf16(gg.x, gg.y), pack_bf16(gg.z, gg.w)};
                    *reinterpret_cast<uint2*>(nbuf + row * 72 + c4 * 4) = v;
                }
            }
        }
        __syncthreads();
    }

    // final reductions over the 16 j-classes (l15)
    #pragma unroll
    for (int mask = 1; mask <= 8; mask <<= 1) {
        #pragma unroll
        for (int ii = 0; ii < 2; ii++) {
            l_acc[ii] += __shfl_xor(l_acc[ii], mask, 64);
            #pragma unroll
            for (int r = 0; r < 4; r++) {
                o0[ii][r] += __shfl_xor(o0[ii][r], mask, 64);
                o1[ii][r] += __shfl_xor(o1[ii][r], mask, 64);
            }
        }
    }
    if (l15 == 0) {
        #pragma unroll
        for (int ii = 0; ii < 2; ii++) {
            const float inv = 1.f / l_acc[ii];
            float* orow = out + ((size_t)(b * N_ + i0 + ii)) * ND_ + h * DH_ + q4 * 4;
            float4 va = {o0[ii][0] * inv, o0[ii][1] * inv, o0[ii][2] * inv, o0[ii][3] * inv};
            float4 vb = {o1[ii][0] * inv, o1[ii][1] * inv, o1[ii][2] * inv, o1[ii][3] * inv};
            *reinterpret_cast<float4*>(orow)      = va;
            *reinterpret_cast<float4*>(orow + 16) = vb;
        }
    }
}

extern "C" void kernel_launch(void* const* d_in, const int* in_sizes, int n_in,
                              void* d_out, int out_size, void* d_ws, size_t ws_size,
                              hipStream_t stream) {
    const float* node = (const float*)d_in[0];
    const float* edge = (const float*)d_in[1];
    const float* Wnq  = (const float*)d_in[2];
    const float* bnq  = (const float*)d_in[3];
    const float* Wnk  = (const float*)d_in[4];
    const float* bnk  = (const float*)d_in[5];
    const float* Wnv  = (const float*)d_in[6];
    const float* bnv  = (const float*)d_in[7];
    const float* Weq  = (const float*)d_in[8];
    const float* beq  = (const float*)d_in[9];
    const float* Wek  = (const float*)d_in[10];
    const float* bek  = (const float*)d_in[11];
    const float* Wev  = (const float*)d_in[12];
    const float* bev  = (const float*)d_in[13];

    char* ws = (char*)d_ws;
    unsigned short* W16 = (unsigned short*)ws;              // 96 KB (pad to 128 KB)
    float* Wt  = (float*)(ws + 131072);                     // 768 KB
    float* Qh  = (float*)(ws + 131072 + 786432);            // 1 MB
    float* KVp = (float*)(ws + 131072 + 786432 + 1048576);  // 2 MB
    float* out = (float*)d_out;

    cvt_w_kernel<<<192, 256, 0, stream>>>(Weq, Wek, Wev, W16);
    trans_w_kernel<<<192, 256, 0, stream>>>(Wnq, Wnk, Wnv, Wt);
    qkv_kernel<<<384, 256, 0, stream>>>(node, Wt, bnq, bnk, bnv, beq, bek, bev, Qh, KVp);
    attn_kernel<<<512, 512, 0, stream>>>(edge, Qh, KVp, W16, out);
}

// Round 10
// 266.914 us; speedup vs baseline: 1.7739x; 1.0212x over previous
//
#include <hip/hip_runtime.h>

typedef __bf16 bf16x8 __attribute__((ext_vector_type(8)));
typedef float  f32x4  __attribute__((ext_vector_type(4)));
typedef unsigned int u32x4 __attribute__((ext_vector_type(4)));

#define B_   2
#define N_   512
#define ND_  256
#define ED_  64
#define NH_  8
#define DH_  32

static __device__ __forceinline__ unsigned pack_bf16(float a, float b) {
    unsigned short ua = __builtin_bit_cast(unsigned short, (__bf16)a);
    unsigned short ub = __builtin_bit_cast(unsigned short, (__bf16)b);
    return (unsigned)ua | ((unsigned)ub << 16);
}

// ---------------- prep kernel 1: edge-weight fp32 -> bf16 (row-major [256][64])
__global__ __launch_bounds__(256) void cvt_w_kernel(
    const float* __restrict__ wq, const float* __restrict__ wk,
    const float* __restrict__ wv, unsigned short* __restrict__ w16)
{
    int id = blockIdx.x * 256 + threadIdx.x;          // 0..49151
    const float* src = (id < 16384) ? wq : (id < 32768 ? wk : wv);
    int idx = id & 16383;
    w16[id] = __builtin_bit_cast(unsigned short, (__bf16)src[idx]);
}

// ---------------- prep kernel 1b: transpose node weights -> Wt[m][k][c] fp32
__global__ __launch_bounds__(256) void trans_w_kernel(
    const float* __restrict__ Wq, const float* __restrict__ Wk,
    const float* __restrict__ Wv, float* __restrict__ Wt)
{
    __shared__ float t[32][33];
    const int bx = blockIdx.x;        // 0..191 = 3 mats * 64 tiles
    const int m  = bx >> 6;
    const int t6 = bx & 63;
    const int cb = (t6 >> 3) << 5;    // c-block
    const int kb = (t6 & 7) << 5;     // k-block
    const float* W = (m == 0) ? Wq : (m == 1 ? Wk : Wv);
    const int tx = threadIdx.x & 31, ty = threadIdx.x >> 5;   // 32 x 8
    #pragma unroll
    for (int s = 0; s < 4; s++)
        t[ty + 8 * s][tx] = W[(size_t)(cb + ty + 8 * s) * ND_ + kb + tx];
    __syncthreads();
    float* dst = Wt + (size_t)m * ND_ * ND_;
    #pragma unroll
    for (int s = 0; s < 4; s++)
        dst[(size_t)(kb + ty + 8 * s) * ND_ + cb + tx] = t[tx][ty + 8 * s];
}

// ------- prep kernel 2: node projections with coalesced (transposed) weights.
// 8 output rows per block. Q -> row-major head-split Qh[bh][i][32].
// K,V -> KVp in MFMA C-fragment order so attn loads are lane-linear:
//   KVp float idx = ((bh*32 + j/16)*4 + set)*256 + (((d>>2)&3)*16 + (j&15))*4 + (d&3)
//   set: 0,1 = K halves (d<16 / d>=16), 2,3 = V halves.
__global__ __launch_bounds__(256) void qkv_kernel(
    const float* __restrict__ node, const float* __restrict__ Wt,
    const float* __restrict__ bnq, const float* __restrict__ bnk,
    const float* __restrict__ bnv, const float* __restrict__ beq,
    const float* __restrict__ bek, const float* __restrict__ bev,
    float* __restrict__ Qh, float* __restrict__ KVp)
{
    __shared__ float xs[8][ND_];
    const int c   = threadIdx.x;
    const int m   = blockIdx.x >> 7;       // 384 blocks: 0=Q 1=K 2=V
    const int grp = blockIdx.x & 127;
    const int g0  = grp * 8;
    #pragma unroll
    for (int s = 0; s < 2; s++) {
        const int f = s * 256 + c;               // float4 index 0..511
        const int r = f >> 6, col4 = (f & 63) * 4;
        const float4 v = *reinterpret_cast<const float4*>(node + (size_t)(g0 + r) * ND_ + col4);
        *reinterpret_cast<float4*>(&xs[r][col4]) = v;
    }
    __syncthreads();

    const float* Wm = Wt + (size_t)m * ND_ * ND_;
    float acc[8] = {};
    for (int k = 0; k < ND_; k += 4) {
        const float w0 = Wm[(size_t)(k + 0) * ND_ + c];
        const float w1 = Wm[(size_t)(k + 1) * ND_ + c];
        const float w2 = Wm[(size_t)(k + 2) * ND_ + c];
        const float w3 = Wm[(size_t)(k + 3) * ND_ + c];
        #pragma unroll
        for (int rr = 0; rr < 8; rr++) {
            const float4 x = *reinterpret_cast<const float4*>(&xs[rr][k]);
            acc[rr] += x.x * w0 + x.y * w1 + x.z * w2 + x.w * w3;
        }
    }
    const float bias = (m == 0) ? (bnq[c] + beq[c])
                     : (m == 1) ? (bnk[c] + bek[c])
                                : (bnv[c] + bev[c]);
    const int h = c >> 5, d = c & 31;
    #pragma unroll
    for (int rr = 0; rr < 8; rr++) {
        const int g  = g0 + rr;
        const int bb = g >> 9, ii = g & (N_ - 1);
        const int bh = bb * NH_ + h;
        const float y = acc[rr] + bias;
        if (m == 0) {
            Qh[((size_t)bh * N_ + ii) * DH_ + d] = y;
        } else {
            const int set = ((m == 1) ? 0 : 2) + (d >> 4);
            const size_t idx = (((size_t)bh * 32 + (ii >> 4)) * 4 + set) * 256
                             + (size_t)((((d >> 2) & 3) * 16 + (ii & 15)) * 4 + (d & 3));
            KVp[idx] = y;
        }
    }
}

// ---------------- main fused kernel: round-9 structure (90 us, VGPR 124,
// zero scratch) with ONE change: the KV register pipeline uses TWO named sets
// alternating by sub parity, refilled IN-PLACE right after their MFMA
// consumers issue. This doubles the KV issue->wait distance (~1 sub -> ~2
// subs, ~450+ cyc > L2 latency) at ZERO extra register cost (the renamed
// Ck/Cv copies are gone; 32 KV regs live, same as before). WAR deps order the
// refill after the consuming MFMAs; each set's wait leaves younger staging
// loads in flight (vmcnt >= 8, never a drain).
__global__ __launch_bounds__(512, 2) void attn_kernel(
    const float* __restrict__ edge,
    const float* __restrict__ Qh, const float* __restrict__ KVp,
    const unsigned short* __restrict__ W16, float* __restrict__ out)
{
    __shared__ unsigned short lds_[2][2][64 * 72];   // [buf][i-row][64 rows * 72]

    const int tid  = threadIdx.x;
    const int lane = tid & 63;
    const int h    = tid >> 6;       // wave id == head
    const int q4   = lane >> 4;
    const int l15  = lane & 15;
    const int blk  = blockIdx.x;     // 0..511
    const int b    = blk >> 8;
    const int i0   = (blk & 255) * 2;
    const int bh   = b * NH_ + h;

    // W A-operand frags: A[m=l15][k=q4*8+kk]; wf[m][half][ks]
    bf16x8 wf[3][2][2];
    #pragma unroll
    for (int m = 0; m < 3; m++)
        #pragma unroll
        for (int hf = 0; hf < 2; hf++)
            #pragma unroll
            for (int ks = 0; ks < 2; ks++) {
                const u32x4* p = reinterpret_cast<const u32x4*>(
                    W16 + m * (ND_ * ED_) + (h * DH_ + hf * 16 + l15) * ED_ + ks * 32 + q4 * 8);
                wf[m][hf][ks] = __builtin_bit_cast(bf16x8, *p);
            }

    // Q C-init (row d = q4*4+r, broadcast over j=l15), for both i rows
    f32x4 Cq[2][2];
    {
        const float* Qrow = Qh + ((size_t)bh * N_ + i0) * DH_;
        Cq[0][0] = *reinterpret_cast<const f32x4*>(Qrow + q4 * 4);
        Cq[0][1] = *reinterpret_cast<const f32x4*>(Qrow + 16 + q4 * 4);
        Cq[1][0] = *reinterpret_cast<const f32x4*>(Qrow + DH_ + q4 * 4);
        Cq[1][1] = *reinterpret_cast<const f32x4*>(Qrow + DH_ + 16 + q4 * 4);
    }

    // lane-linear K/V fragment base: per jg, sets at +0,+64,+128,+192 (f32x4)
    const f32x4* kvb = reinterpret_cast<const f32x4*>(KVp + (size_t)bh * 32 * 1024) + lane;

    const float* eb0 = edge + ((size_t)(b * N_ + i0)) * N_ * ED_;
    const float* eb1 = eb0 + (size_t)N_ * ED_;

    float l_acc[2] = {0.f, 0.f};
    f32x4 o0[2] = {{0.f,0.f,0.f,0.f},{0.f,0.f,0.f,0.f}};
    f32x4 o1[2] = {{0.f,0.f,0.f,0.f},{0.f,0.f,0.f,0.f}};
    const float scale = 0.17677669529663687f;   // 1/sqrt(32)

#define KV_PRE(KA0, KA1, VA0, VA1, JG) do {                                    \
        const f32x4* pp_ = kvb + (size_t)((JG) & 31) * 256;                    \
        KA0 = pp_[0]; KA1 = pp_[64]; VA0 = pp_[128]; VA1 = pp_[192];           \
    } while (0)

// One sub: consume the named set DIRECTLY as MFMA C-operands (both i rows),
// then refill the SAME set for jg+2 (WAR-ordered after the consuming MFMAs),
// then the score/exp/accumulate chains.
#define DO_SUB(SI, KA0, KA1, VA0, VA1) do {                                    \
        const unsigned short* ar0_ = buf0 + ((SI) * 16 + l15) * 72 + q4 * 8;   \
        const unsigned short* ar1_ = buf1 + ((SI) * 16 + l15) * 72 + q4 * 8;   \
        const bf16x8 a00_ = __builtin_bit_cast(bf16x8, *reinterpret_cast<const u32x4*>(ar0_));      \
        const bf16x8 a01_ = __builtin_bit_cast(bf16x8, *reinterpret_cast<const u32x4*>(ar0_ + 32)); \
        const bf16x8 a10_ = __builtin_bit_cast(bf16x8, *reinterpret_cast<const u32x4*>(ar1_));      \
        const bf16x8 a11_ = __builtin_bit_cast(bf16x8, *reinterpret_cast<const u32x4*>(ar1_ + 32)); \
        _Pragma("unroll")                                                      \
        for (int ii = 0; ii < 2; ii++) {                                       \
            const bf16x8 aA = ii ? a10_ : a00_;                                \
            const bf16x8 aB = ii ? a11_ : a01_;                                \
            f32x4 eq0 = __builtin_amdgcn_mfma_f32_16x16x32_bf16(wf[0][0][0], aA, Cq[ii][0], 0, 0, 0); \
            f32x4 eq1 = __builtin_amdgcn_mfma_f32_16x16x32_bf16(wf[0][1][0], aA, Cq[ii][1], 0, 0, 0); \
            f32x4 ek0 = __builtin_amdgcn_mfma_f32_16x16x32_bf16(wf[1][0][0], aA, KA0, 0, 0, 0);       \
            f32x4 ek1 = __builtin_amdgcn_mfma_f32_16x16x32_bf16(wf[1][1][0], aA, KA1, 0, 0, 0);       \
            f32x4 ev0 = __builtin_amdgcn_mfma_f32_16x16x32_bf16(wf[2][0][0], aA, VA0, 0, 0, 0);       \
            f32x4 ev1 = __builtin_amdgcn_mfma_f32_16x16x32_bf16(wf[2][1][0], aA, VA1, 0, 0, 0);       \
            eq0 = __builtin_amdgcn_mfma_f32_16x16x32_bf16(wf[0][0][1], aB, eq0, 0, 0, 0);             \
            eq1 = __builtin_amdgcn_mfma_f32_16x16x32_bf16(wf[0][1][1], aB, eq1, 0, 0, 0);             \
            ek0 = __builtin_amdgcn_mfma_f32_16x16x32_bf16(wf[1][0][1], aB, ek0, 0, 0, 0);             \
            ek1 = __builtin_amdgcn_mfma_f32_16x16x32_bf16(wf[1][1][1], aB, ek1, 0, 0, 0);             \
            ev0 = __builtin_amdgcn_mfma_f32_16x16x32_bf16(wf[2][0][1], aB, ev0, 0, 0, 0);             \
            ev1 = __builtin_amdgcn_mfma_f32_16x16x32_bf16(wf[2][1][1], aB, ev1, 0, 0, 0);             \
            float ta = eq0[0]*ek0[0] + eq0[1]*ek0[1];                          \
            float tb = eq0[2]*ek0[2] + eq0[3]*ek0[3];                          \
            float tc = eq1[0]*ek1[0] + eq1[1]*ek1[1];                          \
            float td = eq1[2]*ek1[2] + eq1[3]*ek1[3];                          \
            float t = (ta + tb) + (tc + td);                                   \
            t += __shfl_xor(t, 16, 64);                                        \
            t += __shfl_xor(t, 32, 64);                                        \
            const float p = __expf(fmaf(t, scale, -4.f));                      \
            l_acc[ii] += p;                                                    \
            o0[ii] += ev0 * p;                                                 \
            o1[ii] += ev1 * p;                                                 \
        }                                                                      \
        KV_PRE(KA0, KA1, VA0, VA1, ch * 4 + (SI) + 2);                         \
    } while (0)

    // ---- prologue: KV sets for jg=0,1 FIRST (oldest in queue), then chunk 0
    f32x4 k0a, k0b, v0a, v0b, k1a, k1b, v1a, v1b;
    KV_PRE(k0a, k0b, v0a, v0b, 0);
    KV_PRE(k1a, k1b, v1a, v1b, 1);

    float4 g[2][2];
    {
        const float4* e0 = reinterpret_cast<const float4*>(eb0);
        const float4* e1 = reinterpret_cast<const float4*>(eb1);
        g[0][0] = e0[tid]; g[0][1] = e0[tid + 512];
        g[1][0] = e1[tid]; g[1][1] = e1[tid + 512];
    }
    #pragma unroll
    for (int ii = 0; ii < 2; ii++) {
        unsigned short* buf = lds_[0][ii];
        #pragma unroll
        for (int pt = 0; pt < 2; pt++) {
            const float4 gg = g[ii][pt];
            const int f = tid + pt * 512;
            const int row = f >> 4, c4 = f & 15;
            uint2 v = {pack_bf16(gg.x, gg.y), pack_bf16(gg.z, gg.w)};
            *reinterpret_cast<uint2*>(buf + row * 72 + c4 * 4) = v;
        }
    }
    __syncthreads();

    #pragma unroll 1
    for (int ch = 0; ch < 8; ch++) {
        if (ch < 7) {   // issue next chunk's staging loads (consumed at chunk end)
            const float4* e0 = reinterpret_cast<const float4*>(eb0 + (ch + 1) * 4096);
            const float4* e1 = reinterpret_cast<const float4*>(eb1 + (ch + 1) * 4096);
            g[0][0] = e0[tid]; g[0][1] = e0[tid + 512];
            g[1][0] = e1[tid]; g[1][1] = e1[tid + 512];
        }
        const unsigned short* buf0 = lds_[ch & 1][0];
        const unsigned short* buf1 = lds_[ch & 1][1];

        DO_SUB(0, k0a, k0b, v0a, v0b);   // consumes jg=ch*4+0, refills for +2
        DO_SUB(1, k1a, k1b, v1a, v1b);   // consumes jg=ch*4+1, refills for +3
        DO_SUB(2, k0a, k0b, v0a, v0b);   // consumes jg=ch*4+2, refills for +4
        DO_SUB(3, k1a, k1b, v1a, v1b);   // consumes jg=ch*4+3, refills for +5

        if (ch < 7) {   // pack+store next chunk into the other buffer
            #pragma unroll
            for (int ii = 0; ii < 2; ii++) {
                unsigned short* nbuf = lds_[(ch + 1) & 1][ii];
                #pragma unroll
                for (int pt = 0; pt < 2; pt++) {
                    const float4 gg = g[ii][pt];
                    const int f = tid + pt * 512;
                    const int row = f >> 4, c4 = f & 15;
                    uint2 v = {pack_bf16(gg.x, gg.y), pack_bf16(gg.z, gg.w)};
                    *reinterpret_cast<uint2*>(nbuf + row * 72 + c4 * 4) = v;
                }
            }
        }
        __syncthreads();
    }
#undef KV_PRE
#undef DO_SUB

    // final reductions over the 16 j-classes (l15)
    #pragma unroll
    for (int mask = 1; mask <= 8; mask <<= 1) {
        #pragma unroll
        for (int ii = 0; ii < 2; ii++) {
            l_acc[ii] += __shfl_xor(l_acc[ii], mask, 64);
            #pragma unroll
            for (int r = 0; r < 4; r++) {
                o0[ii][r] += __shfl_xor(o0[ii][r], mask, 64);
                o1[ii][r] += __shfl_xor(o1[ii][r], mask, 64);
            }
        }
    }
    if (l15 == 0) {
        #pragma unroll
        for (int ii = 0; ii < 2; ii++) {
            const float inv = 1.f / l_acc[ii];
            float* orow = out + ((size_t)(b * N_ + i0 + ii)) * ND_ + h * DH_ + q4 * 4;
            float4 va = {o0[ii][0] * inv, o0[ii][1] * inv, o0[ii][2] * inv, o0[ii][3] * inv};
            float4 vb = {o1[ii][0] * inv, o1[ii][1] * inv, o1[ii][2] * inv, o1[ii][3] * inv};
            *reinterpret_cast<float4*>(orow)      = va;
            *reinterpret_cast<float4*>(orow + 16) = vb;
        }
    }
}

extern "C" void kernel_launch(void* const* d_in, const int* in_sizes, int n_in,
                              void* d_out, int out_size, void* d_ws, size_t ws_size,
                              hipStream_t stream) {
    const float* node = (const float*)d_in[0];
    const float* edge = (const float*)d_in[1];
    const float* Wnq  = (const float*)d_in[2];
    const float* bnq  = (const float*)d_in[3];
    const float* Wnk  = (const float*)d_in[4];
    const float* bnk  = (const float*)d_in[5];
    const float* Wnv  = (const float*)d_in[6];
    const float* bnv  = (const float*)d_in[7];
    const float* Weq  = (const float*)d_in[8];
    const float* beq  = (const float*)d_in[9];
    const float* Wek  = (const float*)d_in[10];
    const float* bek  = (const float*)d_in[11];
    const float* Wev  = (const float*)d_in[12];
    const float* bev  = (const float*)d_in[13];

    char* ws = (char*)d_ws;
    unsigned short* W16 = (unsigned short*)ws;              // 96 KB (pad to 128 KB)
    float* Wt  = (float*)(ws + 131072);                     // 768 KB
    float* Qh  = (float*)(ws + 131072 + 786432);            // 1 MB
    float* KVp = (float*)(ws + 131072 + 786432 + 1048576);  // 2 MB
    float* out = (float*)d_out;

    cvt_w_kernel<<<192, 256, 0, stream>>>(Weq, Wek, Wev, W16);
    trans_w_kernel<<<192, 256, 0, stream>>>(Wnq, Wnk, Wnv, Wt);
    qkv_kernel<<<384, 256, 0, stream>>>(node, Wt, bnq, bnk, bnv, beq, bek, bev, Qh, KVp);
    attn_kernel<<<512, 512, 0, stream>>>(edge, Qh, KVp, W16, out);
}